// Round 1
// baseline (155.010 us; speedup 1.0000x reference)
//
#include <hip/hip_runtime.h>
#include <hip/hip_bf16.h>

#define PATCH 10
#define CELLS 1000  // 10*10*10

// One block per depo. Phase 1: 33 threads compute cdf[3][11] in LDS.
// Phase 2: 30 threads diff -> w[3][10]. Phase 3: 250 threads write 4 cells
// each as a float4 (fully coalesced, 1000 contiguous floats per depo).
__global__ __launch_bounds__(256) void raster_kernel(
    const float* __restrict__ sigma,   // [N,3]
    const float* __restrict__ time,    // [N]
    const float* __restrict__ charge,  // [N]
    const float* __restrict__ tail,    // [N,3]
    const float* __restrict__ gs,      // [3]
    const float* __restrict__ nsig,    // [1]
    float* __restrict__ out_r,         // [N,10,10,10]
    float* __restrict__ out_off,       // [N,3] (int values stored as f32)
    int n)
{
    const int depo = blockIdx.x;
    if (depo >= n) return;

    __shared__ float cdf[3][12];   // 11 used, pad to 12
    __shared__ float w[3][12];     // 10 used
    __shared__ float s_charge;

    const int tid = threadIdx.x;

    if (tid < 33) {
        const int dim = tid / 11;
        const int k   = tid % 11;
        // center = [tail[:,1], tail[:,2], time]
        float c;
        if (dim == 0)      c = tail[depo * 3 + 1];
        else if (dim == 1) c = tail[depo * 3 + 2];
        else               c = time[depo];
        const float sg = sigma[depo * 3 + dim];
        const float sp = gs[dim];
        const float ns = nsig[0];
        const float imin = floorf((c - ns * sg) / sp);
        const float edge = (imin + (float)k) * sp;
        const float z = (edge - c) / (1.41421356237f * sg);
        cdf[dim][k] = 0.5f * (1.0f + erff(z));
        if (k == 0) {
            // offsets = int32(imin); stored as float32 (exactly representable)
            out_off[(size_t)depo * 3 + dim] = (float)(int)imin;
        }
    }
    if (tid == 33) s_charge = charge[depo];
    __syncthreads();

    if (tid < 30) {
        const int dim = tid / 10;
        const int k   = tid % 10;
        w[dim][k] = cdf[dim][k + 1] - cdf[dim][k];
    }
    __syncthreads();

    if (tid < 250) {
        const float q = s_charge;
        const int base = tid * 4;
        float r[4];
#pragma unroll
        for (int t = 0; t < 4; ++t) {
            const int c = base + t;
            const int i = c / 100;
            const int j = (c / 10) % 10;
            const int k = c % 10;
            r[t] = q * w[0][i] * w[1][j] * w[2][k];
        }
        float4 v;
        v.x = r[0]; v.y = r[1]; v.z = r[2]; v.w = r[3];
        reinterpret_cast<float4*>(out_r + (size_t)depo * CELLS)[tid] = v;
    }
}

extern "C" void kernel_launch(void* const* d_in, const int* in_sizes, int n_in,
                              void* d_out, int out_size, void* d_ws, size_t ws_size,
                              hipStream_t stream) {
    const float* sigma  = (const float*)d_in[0];  // [N,3]
    const float* time_  = (const float*)d_in[1];  // [N]
    const float* charge = (const float*)d_in[2];  // [N]
    const float* tail   = (const float*)d_in[3];  // [N,3]
    const float* gs     = (const float*)d_in[4];  // [3]
    const float* nsig   = (const float*)d_in[5];  // [1]

    const int n = in_sizes[1];  // time has N elements

    float* out_r   = (float*)d_out;                       // N*1000 floats
    float* out_off = (float*)d_out + (size_t)n * CELLS;   // N*3 values

    raster_kernel<<<n, 256, 0, stream>>>(sigma, time_, charge, tail, gs, nsig,
                                         out_r, out_off, n);
}

// Round 3
// 81.555 us; speedup vs baseline: 1.9007x; 1.9007x over previous
//
#include <hip/hip_runtime.h>
#include <hip/hip_bf16.h>

#define PATCH 10
#define CELLS 1000   // 10*10*10
#define DPB   16     // depos per block (100000 % 16 == 0 -> 6250 blocks)

typedef float vfloat4 __attribute__((ext_vector_type(4)));

// 512 threads, 16 depos per block.
// Phase 1: threads 0..479 -> one (depo,dim,k) each: compute w[d][dim*10+k]
//          (2 erfs), k==0 threads also write offsets; (dim==0,k==0) loads q.
// Phase 2: threads 0..499 -> 8 unrolled iterations; thread owns a fixed
//          float4 cell-group (indices precomputed once), iterates over depos.
//          32 KB of uninterrupted nontemporal float4 stores per block.
__global__ __launch_bounds__(512) void raster_kernel(
    const float* __restrict__ sigma,   // [N,3]
    const float* __restrict__ time,    // [N]
    const float* __restrict__ charge,  // [N]
    const float* __restrict__ tail,    // [N,3]
    const float* __restrict__ gs,      // [3]
    const float* __restrict__ nsig,    // [1]
    float* __restrict__ out_r,         // [N,10,10,10]
    float* __restrict__ out_off,       // [N,3] (int values stored as f32)
    int n)
{
    const int d0  = blockIdx.x * DPB;
    const int tid = threadIdx.x;

    __shared__ float wq[DPB][32];   // [d][0..29]=w, [30]=charge

    if (tid < DPB * 30) {
        const int d   = tid / 30;
        const int r   = tid % 30;
        const int dim = r / 10;
        const int k   = r % 10;
        const int depo = d0 + d;
        if (depo < n) {
            float c;
            if (dim == 0)      c = tail[depo * 3 + 1];
            else if (dim == 1) c = tail[depo * 3 + 2];
            else               c = time[depo];
            const float sg = sigma[depo * 3 + dim];
            const float sp = gs[dim];
            const float ns = nsig[0];
            const float imin = floorf((c - ns * sg) / sp);
            const float inv  = 1.0f / (1.41421356237309f * sg);
            const float e0 = (imin + (float)k) * sp;
            const float e1 = (imin + (float)(k + 1)) * sp;
            const float cdf0 = 0.5f * (1.0f + erff((e0 - c) * inv));
            const float cdf1 = 0.5f * (1.0f + erff((e1 - c) * inv));
            wq[d][dim * 10 + k] = cdf1 - cdf0;
            if (k == 0) {
                out_off[(size_t)depo * 3 + dim] = (float)(int)imin;
                if (dim == 0) wq[d][30] = charge[depo];
            }
        }
    }
    __syncthreads();

    if (tid < 500) {
        const int half = (tid >= 250) ? 1 : 0;
        const int c4   = tid - 250 * half;       // float4 index within depo
        const int cell0 = c4 * 4;

        // Per-component w indices, fixed for this thread across all depos.
        int a0[4], a1[4], a2[4];
#pragma unroll
        for (int c = 0; c < 4; ++c) {
            const int cell = cell0 + c;
            a0[c] = cell / 100;
            a1[c] = 10 + (cell / 10) % 10;
            a2[c] = 20 + cell % 10;
        }

#pragma unroll
        for (int it = 0; it < DPB / 2; ++it) {
            const int d    = it * 2 + half;
            const int depo = d0 + d;
            if (depo < n) {
                const float q = wq[d][30];
                vfloat4 v;
                v.x = q * wq[d][a0[0]] * wq[d][a1[0]] * wq[d][a2[0]];
                v.y = q * wq[d][a0[1]] * wq[d][a1[1]] * wq[d][a2[1]];
                v.z = q * wq[d][a0[2]] * wq[d][a1[2]] * wq[d][a2[2]];
                v.w = q * wq[d][a0[3]] * wq[d][a1[3]] * wq[d][a2[3]];
                vfloat4* dst = reinterpret_cast<vfloat4*>(out_r + (size_t)depo * CELLS) + c4;
                __builtin_nontemporal_store(v, dst);
            }
        }
    }
}

extern "C" void kernel_launch(void* const* d_in, const int* in_sizes, int n_in,
                              void* d_out, int out_size, void* d_ws, size_t ws_size,
                              hipStream_t stream) {
    const float* sigma  = (const float*)d_in[0];  // [N,3]
    const float* time_  = (const float*)d_in[1];  // [N]
    const float* charge = (const float*)d_in[2];  // [N]
    const float* tail   = (const float*)d_in[3];  // [N,3]
    const float* gs     = (const float*)d_in[4];  // [3]
    const float* nsig   = (const float*)d_in[5];  // [1]

    const int n = in_sizes[1];  // time has N elements

    float* out_r   = (float*)d_out;                       // N*1000 floats
    float* out_off = (float*)d_out + (size_t)n * CELLS;   // N*3 values

    const int grid = (n + DPB - 1) / DPB;
    raster_kernel<<<grid, 512, 0, stream>>>(sigma, time_, charge, tail, gs, nsig,
                                            out_r, out_off, n);
}